// Round 9
// baseline (550.683 us; speedup 1.0000x reference)
//
#include <hip/hip_runtime.h>

typedef unsigned short u16;
typedef unsigned int   u32;
typedef __bf16 bf16_t;
typedef bf16_t bf16x8 __attribute__((ext_vector_type(8)));
typedef float  floatx4 __attribute__((ext_vector_type(4)));

#define B_    2
#define QS    1024
#define HID_  2048
#define NH_   32
#define NKV_  8
#define HD_   64
#define KBN_  512
#define TOPK_ 100
#define FS    5120   // fused projection row stride: q|k|v|kbq = 0|2048|2560|3072

__device__ __forceinline__ float b2f(u16 u) {
  union { u32 i; float f; } x; x.i = ((u32)u) << 16; return x.f;
}
__device__ __forceinline__ u16 f2b(float f) {
  union { float f; u32 i; } x; x.f = f;
  u32 r = x.i + 0x7fffu + ((x.i >> 16) & 1u);
  return (u16)(r >> 16);
}
__device__ __forceinline__ void async16(const u16* g, u16* l) {
  __builtin_amdgcn_global_load_lds(
      (const __attribute__((address_space(1))) unsigned int*)g,
      (__attribute__((address_space(3))) unsigned int*)l, 16, 0, 0);
}

// ---- one launch: hs/kb casts + 7 weight transposes + hssum ----
// [0,4096) Wq | [4096,5120) Wk | [5120,6144) Wv | [6144,10240) Wqn
// [10240,11264) Wkbk | [11264,12288) Wkbv | [12288,16384) Wo->WTo
// [16384,20480) cast hs | [20480,22528) cast kb | [22528,22656) hssum
__global__ __launch_bounds__(256)
void tc7_k(const float* __restrict__ Wq, const float* __restrict__ Wk,
           const float* __restrict__ Wv, const float* __restrict__ Wqn,
           const float* __restrict__ Wkbk, const float* __restrict__ Wkbv,
           const float* __restrict__ Wo, u16* __restrict__ WT,
           u16* __restrict__ WTkb, u16* __restrict__ WTo,
           const float* __restrict__ hs, const float* __restrict__ kb,
           u16* __restrict__ hsb, u16* __restrict__ kbb,
           double* __restrict__ partH) {
  int id = blockIdx.x, t = threadIdx.x;
  if (id >= 22528) {  // hssum branch (partial column sums of hs, double)
    int l = id - 22528;
    int qc = l & 63, b = l >> 6;
    double a[8] = {0, 0, 0, 0, 0, 0, 0, 0};
    for (int qq = 0; qq < 16; ++qq) {
      const float* row = hs + (size_t)(b * QS + qc * 16 + qq) * HID_;
#pragma unroll
      for (int m = 0; m < 8; ++m) a[m] += (double)row[m * 256 + t];
    }
#pragma unroll
    for (int m = 0; m < 8; ++m)
      partH[(size_t)qc * (B_ * HID_) + b * HID_ + m * 256 + t] = a[m];
    return;
  }
  if (id >= 16384) {  // cast branch (no LDS, no sync)
    const float* x; u16* y; int j;
    if (id < 20480) { x = hs; y = hsb; j = (id - 16384) * 256 + t; }
    else            { x = kb; y = kbb; j = (id - 20480) * 256 + t; }
    float4 v = ((const float4*)x)[j];
    ((uint2*)y)[j] = make_uint2((u32)f2b(v.x) | ((u32)f2b(v.y) << 16),
                                (u32)f2b(v.z) | ((u32)f2b(v.w) << 16));
    return;
  }
  const float* W; u16* D; int N, bx, by;
  if (id < 4096)       { W = Wq;   D = WT;                        N = 2048; int l = id;         bx = l & 63; by = l >> 6; }
  else if (id < 5120)  { W = Wk;   D = WT + (size_t)2048 * 2048;  N = 512;  int l = id - 4096;  bx = l & 15; by = l >> 4; }
  else if (id < 6144)  { W = Wv;   D = WT + (size_t)2560 * 2048;  N = 512;  int l = id - 5120;  bx = l & 15; by = l >> 4; }
  else if (id < 10240) { W = Wqn;  D = WT + (size_t)3072 * 2048;  N = 2048; int l = id - 6144;  bx = l & 63; by = l >> 6; }
  else if (id < 11264) { W = Wkbk; D = WTkb;                      N = 512;  int l = id - 10240; bx = l & 15; by = l >> 4; }
  else if (id < 12288) { W = Wkbv; D = WTkb + (size_t)512 * 2048; N = 512;  int l = id - 11264; bx = l & 15; by = l >> 4; }
  else                 { W = Wo;   D = WTo;                       N = 2048; int l = id - 12288; bx = l & 63; by = l >> 6; }
  const int K = 2048;
  __shared__ float tile[32][33];
  int n0 = bx * 32, k0 = by * 32;
  int tx = t & 31, ty = t >> 5;
#pragma unroll
  for (int i = 0; i < 32; i += 8)
    tile[ty + i][tx] = W[(size_t)(k0 + ty + i) * N + n0 + tx];
  __syncthreads();
#pragma unroll
  for (int i = 0; i < 32; i += 8)
    D[(size_t)(n0 + ty + i) * K + k0 + tx] = f2b(tile[tx][ty + i]);
}

// ---- combined GEMM 256x256 8-phase: fused proj (160) + kb proj (16) + selS2 (256) --
// blocks [0,176) = GEMM (XCD-swizzled), [176,432) = selS2 filler on idle CUs.
__global__ __launch_bounds__(512, 2)
void gemm256j(const u16* __restrict__ A0, const u16* __restrict__ B0,
              u16* __restrict__ C0, const u16* __restrict__ A1,
              const u16* __restrict__ B1, u16* __restrict__ C1, int K,
              const double* __restrict__ partH, const float* __restrict__ Wqn,
              double* __restrict__ partS) {
  __shared__ __align__(16) u16 sm[65536];  // 128 KiB: [buf2][op2][kk2][256][32]
  const int tid = threadIdx.x, lane = tid & 63, w = tid >> 6;
  int orig = blockIdx.x;
  if (orig >= 176) {  // ---- selS2: S-partials = (col-sum hs) @ Wqn (double) ----
    int l = orig - 176;
    int chunk = l & 127, b = l >> 7, j = tid;
    double* tmpd = (double*)sm;        // 1024 doubles (aliased onto sm)
    double* hsl  = tmpd + 1024;        // 16 doubles
    int g = j >> 6, d = j & 63;
    int c0 = chunk * 16;
    {
      int ch = j >> 4, cc = j & 15;
      tmpd[ch * 16 + cc]        = partH[(size_t)ch * (B_ * HID_) + b * HID_ + c0 + cc];
      tmpd[(ch + 32) * 16 + cc] = partH[(size_t)(ch + 32) * (B_ * HID_) + b * HID_ + c0 + cc];
    }
    __syncthreads();
    if (j < 16) {
      double a = 0.0;
      for (int ch = 0; ch < 64; ++ch) a += tmpd[ch * 16 + j];   // red_d order
      hsl[j] = a;
    }
    __syncthreads();
    double acc = 0.0;
    for (int cc = 0; cc < 16; ++cc) {
      int c = c0 + cc;
      const float* wq = Wqn + (size_t)c * HID_ + g * 256 + d;
      acc += hsl[cc] *
             ((double)wq[0] + (double)wq[64] + (double)wq[128] + (double)wq[192]);
    }
    partS[(size_t)chunk * (B_ * 512) + b * 512 + j] = acc;
    return;
  }
  const int wr = w >> 2, wc = w & 3;
  int swz = (orig & 7) * 22 + (orig >> 3);  // XCD-contiguous, bijective (176=8*22)
  const u16 *A, *BT; u16* C; int CS, bx, by;
  if (swz < 160) { A = A0; BT = B0; C = C0; CS = FS;   bx = swz % 20; by = swz / 20; }
  else { int t2 = swz - 160; A = A1; BT = B1; C = C1; CS = 1024; bx = t2 & 3; by = t2 >> 2; }
  int m0 = by << 8, n0 = bx << 8;
  const int NT = K >> 6;

  int lr = lane >> 2;
  int colsw = ((lane & 3) * 8) ^ ((lane & 32) ? 16 : 0);  // inverse-swizzled source col
  const u16* gA[2][2]; const u16* gB[2][2];
  int lA[2][2];
#pragma unroll
  for (int h = 0; h < 2; ++h)
#pragma unroll
    for (int j = 0; j < 2; ++j) {
      int ij = 2 * w + j, kk = ij >> 3, rb = (ij & 7) * 16;
      gA[h][j] = A + (size_t)(m0 + h * 128 + rb + lr) * K + kk * 32 + colsw;
      gB[h][j] = BT + (size_t)(n0 + h * 128 + rb + lr) * K + kk * 32 + colsw;
      lA[h][j] = kk * 8192 + (h * 128 + rb) * 32;
    }
  int fsw = ((lane >> 4) * 8) ^ ((lane & 8) ? 16 : 0);
  int aoff = (wr * 128 + (lane & 15)) * 32 + fsw;
  int boff = 16384 + (wc * 64 + (lane & 15)) * 32 + fsw;

  floatx4 acc[8][4];
#pragma unroll
  for (int i = 0; i < 8; ++i)
#pragma unroll
    for (int j = 0; j < 4; ++j) acc[i][j] = (floatx4){0.f, 0.f, 0.f, 0.f};
  bf16x8 a[4][2], b[4][2];

#define STG_(g, l, u) async16((g) + (size_t)(u) * 64, &sm[(((u) & 1) << 15) + (l)])
#define BAR_ do { asm volatile("" ::: "memory"); __builtin_amdgcn_s_barrier(); \
                  asm volatile("" ::: "memory"); } while (0)
#define LG0_ do { asm volatile("s_waitcnt lgkmcnt(0)" ::: "memory"); \
                  __builtin_amdgcn_sched_barrier(0); } while (0)

  STG_(gA[0][0], lA[0][0], 0); STG_(gA[0][1], lA[0][1], 0);
  STG_(gA[1][0], lA[1][0], 0); STG_(gA[1][1], lA[1][1], 0);
  STG_(gB[0][0], lA[0][0] + 16384, 0); STG_(gB[0][1], lA[0][1] + 16384, 0);
  STG_(gB[1][0], lA[1][0] + 16384, 0); STG_(gB[1][1], lA[1][1] + 16384, 0);
  if (NT > 1) {
    STG_(gB[0][0], lA[0][0] + 16384, 1); STG_(gB[0][1], lA[0][1] + 16384, 1);
    STG_(gA[0][0], lA[0][0], 1); STG_(gA[0][1], lA[0][1], 1);
    asm volatile("s_waitcnt vmcnt(4)" ::: "memory");
  } else {
    asm volatile("s_waitcnt vmcnt(0)" ::: "memory");
  }
  BAR_;

  for (int u = 0; u < NT; ++u) {
    const int cb = (u & 1) << 15;
    // ---- P1
#pragma unroll
    for (int kk = 0; kk < 2; ++kk) {
#pragma unroll
      for (int mi = 0; mi < 4; ++mi)
        a[mi][kk] = *(const bf16x8*)&sm[cb + kk * 8192 + aoff + mi * 512];
#pragma unroll
      for (int ni = 0; ni < 2; ++ni)
        b[ni][kk] = *(const bf16x8*)&sm[cb + kk * 8192 + boff + ni * 512];
    }
    if (u + 1 < NT) { STG_(gA[1][0], lA[1][0], u + 1); STG_(gA[1][1], lA[1][1], u + 1); }
    BAR_; LG0_;
    __builtin_amdgcn_s_setprio(1);
#pragma unroll
    for (int mi = 0; mi < 4; ++mi)
#pragma unroll
      for (int ni = 0; ni < 2; ++ni)
#pragma unroll
        for (int kk = 0; kk < 2; ++kk)
          acc[mi][ni] = __builtin_amdgcn_mfma_f32_16x16x32_bf16(
              a[mi][kk], b[ni][kk], acc[mi][ni], 0, 0, 0);
    __builtin_amdgcn_s_setprio(0);
    BAR_;
    // ---- P2
#pragma unroll
    for (int kk = 0; kk < 2; ++kk)
#pragma unroll
      for (int ni = 0; ni < 2; ++ni)
        b[2 + ni][kk] = *(const bf16x8*)&sm[cb + kk * 8192 + boff + (2 + ni) * 512];
    if (u + 1 < NT) { STG_(gB[1][0], lA[1][0] + 16384, u + 1);
                      STG_(gB[1][1], lA[1][1] + 16384, u + 1); }
    BAR_; LG0_;
    __builtin_amdgcn_s_setprio(1);
#pragma unroll
    for (int mi = 0; mi < 4; ++mi)
#pragma unroll
      for (int ni = 0; ni < 2; ++ni)
#pragma unroll
        for (int kk = 0; kk < 2; ++kk)
          acc[mi][2 + ni] = __builtin_amdgcn_mfma_f32_16x16x32_bf16(
              a[mi][kk], b[2 + ni][kk], acc[mi][2 + ni], 0, 0, 0);
    __builtin_amdgcn_s_setprio(0);
    BAR_;
    // ---- P3
#pragma unroll
    for (int kk = 0; kk < 2; ++kk)
#pragma unroll
      for (int mi = 0; mi < 4; ++mi)
        a[mi][kk] = *(const bf16x8*)&sm[cb + kk * 8192 + aoff + 2048 + mi * 512];
    if (u + 2 < NT) { STG_(gB[0][0], lA[0][0] + 16384, u + 2);
                      STG_(gB[0][1], lA[0][1] + 16384, u + 2); }
    BAR_; LG0_;
    __builtin_amdgcn_s_setprio(1);
#pragma unroll
    for (int mi = 0; mi < 4; ++mi)
#pragma unroll
      for (int ni = 0; ni < 2; ++ni)
#pragma unroll
        for (int kk = 0; kk < 2; ++kk)
          acc[4 + mi][2 + ni] = __builtin_amdgcn_mfma_f32_16x16x32_bf16(
              a[mi][kk], b[2 + ni][kk], acc[4 + mi][2 + ni], 0, 0, 0);
    __builtin_amdgcn_s_setprio(0);
    BAR_;
    // ---- P4
    if (u + 2 < NT) {
      STG_(gA[0][0], lA[0][0], u + 2); STG_(gA[0][1], lA[0][1], u + 2);
      asm volatile("s_waitcnt vmcnt(4)" ::: "memory");
    } else {
      asm volatile("s_waitcnt vmcnt(0)" ::: "memory");
    }
    BAR_;
    __builtin_amdgcn_s_setprio(1);
#pragma unroll
    for (int mi = 0; mi < 4; ++mi)
#pragma unroll
      for (int ni = 0; ni < 2; ++ni)
#pragma unroll
        for (int kk = 0; kk < 2; ++kk)
          acc[4 + mi][ni] = __builtin_amdgcn_mfma_f32_16x16x32_bf16(
              a[mi][kk], b[ni][kk], acc[4 + mi][ni], 0, 0, 0);
    __builtin_amdgcn_s_setprio(0);
    BAR_;
  }
#undef STG_
#undef BAR_
#undef LG0_
  int quad = lane >> 4, col = lane & 15;
#pragma unroll
  for (int mi = 0; mi < 8; ++mi)
#pragma unroll
    for (int ni = 0; ni < 4; ++ni)
#pragma unroll
      for (int rr = 0; rr < 4; ++rr)
        C[(size_t)(m0 + wr * 128 + mi * 16 + quad * 4 + rr) * CS +
          n0 + wc * 64 + ni * 16 + col] = f2b(acc[mi][ni][rr]);
}

// ---- split-K GEMM 256x256 8-phase, serial-K fused reduction (CK pattern) ----
// Each slice stores its f32 partial; last block per tile (device-scope counter)
// sums slices in FIXED order 0..nslice-1 (same association as round-6 redp) and
// writes Out. cnt[ntiles] must be zeroed before launch.
__global__ __launch_bounds__(512, 2)
void gemm256s(const u16* __restrict__ A, const u16* __restrict__ BT,
              float* __restrict__ P, int* __restrict__ cnt,
              float* __restrict__ Out, int N, int LDK, int Kl, int ntiles) {
  __shared__ __align__(16) u16 sm[65536];  // 128 KiB
  const int tid = threadIdx.x, lane = tid & 63, w = tid >> 6;
  const int wr = w >> 2, wc = w & 3;
  const int nbx = N >> 8;
  int nwg = gridDim.x, orig = blockIdx.x, swz = orig;
  if ((nwg & 7) == 0) swz = (orig & 7) * (nwg >> 3) + (orig >> 3);  // XCD-contig
  int tile = swz % ntiles, slice = swz / ntiles;
  const int nslice = nwg / ntiles;
  int bx = tile % nbx, by = tile / nbx;
  int m0 = by << 8, n0 = bx << 8;
  const int NT = Kl >> 6;
  const u16* As = A + (size_t)slice * Kl;
  const u16* Bs = BT + (size_t)slice * Kl;

  int lr = lane >> 2;
  int colsw = ((lane & 3) * 8) ^ ((lane & 32) ? 16 : 0);
  const u16* gA[2][2]; const u16* gB[2][2];
  int lA[2][2];
#pragma unroll
  for (int h = 0; h < 2; ++h)
#pragma unroll
    for (int j = 0; j < 2; ++j) {
      int ij = 2 * w + j, kk = ij >> 3, rb = (ij & 7) * 16;
      gA[h][j] = As + (size_t)(m0 + h * 128 + rb + lr) * LDK + kk * 32 + colsw;
      gB[h][j] = Bs + (size_t)(n0 + h * 128 + rb + lr) * LDK + kk * 32 + colsw;
      lA[h][j] = kk * 8192 + (h * 128 + rb) * 32;
    }
  int fsw = ((lane >> 4) * 8) ^ ((lane & 8) ? 16 : 0);
  int aoff = (wr * 128 + (lane & 15)) * 32 + fsw;
  int boff = 16384 + (wc * 64 + (lane & 15)) * 32 + fsw;

  floatx4 acc[8][4];
#pragma unroll
  for (int i = 0; i < 8; ++i)
#pragma unroll
    for (int j = 0; j < 4; ++j) acc[i][j] = (floatx4){0.f, 0.f, 0.f, 0.f};
  bf16x8 a[4][2], b[4][2];

#define STG_(g, l, u) async16((g) + (size_t)(u) * 64, &sm[(((u) & 1) << 15) + (l)])
#define BAR_ do { asm volatile("" ::: "memory"); __builtin_amdgcn_s_barrier(); \
                  asm volatile("" ::: "memory"); } while (0)
#define LG0_ do { asm volatile("s_waitcnt lgkmcnt(0)" ::: "memory"); \
                  __builtin_amdgcn_sched_barrier(0); } while (0)

  STG_(gA[0][0], lA[0][0], 0); STG_(gA[0][1], lA[0][1], 0);
  STG_(gA[1][0], lA[1][0], 0); STG_(gA[1][1], lA[1][1], 0);
  STG_(gB[0][0], lA[0][0] + 16384, 0); STG_(gB[0][1], lA[0][1] + 16384, 0);
  STG_(gB[1][0], lA[1][0] + 16384, 0); STG_(gB[1][1], lA[1][1] + 16384, 0);
  if (NT > 1) {
    STG_(gB[0][0], lA[0][0] + 16384, 1); STG_(gB[0][1], lA[0][1] + 16384, 1);
    STG_(gA[0][0], lA[0][0], 1); STG_(gA[0][1], lA[0][1], 1);
    asm volatile("s_waitcnt vmcnt(4)" ::: "memory");
  } else {
    asm volatile("s_waitcnt vmcnt(0)" ::: "memory");
  }
  BAR_;

  for (int u = 0; u < NT; ++u) {
    const int cb = (u & 1) << 15;
    // ---- P1
#pragma unroll
    for (int kk = 0; kk < 2; ++kk) {
#pragma unroll
      for (int mi = 0; mi < 4; ++mi)
        a[mi][kk] = *(const bf16x8*)&sm[cb + kk * 8192 + aoff + mi * 512];
#pragma unroll
      for (int ni = 0; ni < 2; ++ni)
        b[ni][kk] = *(const bf16x8*)&sm[cb + kk * 8192 + boff + ni * 512];
    }
    if (u + 1 < NT) { STG_(gA[1][0], lA[1][0], u + 1); STG_(gA[1][1], lA[1][1], u + 1); }
    BAR_; LG0_;
    __builtin_amdgcn_s_setprio(1);
#pragma unroll
    for (int mi = 0; mi < 4; ++mi)
#pragma unroll
      for (int ni = 0; ni < 2; ++ni)
#pragma unroll
        for (int kk = 0; kk < 2; ++kk)
          acc[mi][ni] = __builtin_amdgcn_mfma_f32_16x16x32_bf16(
              a[mi][kk], b[ni][kk], acc[mi][ni], 0, 0, 0);
    __builtin_amdgcn_s_setprio(0);
    BAR_;
    // ---- P2
#pragma unroll
    for (int kk = 0; kk < 2; ++kk)
#pragma unroll
      for (int ni = 0; ni < 2; ++ni)
        b[2 + ni][kk] = *(const bf16x8*)&sm[cb + kk * 8192 + boff + (2 + ni) * 512];
    if (u + 1 < NT) { STG_(gB[1][0], lA[1][0] + 16384, u + 1);
                      STG_(gB[1][1], lA[1][1] + 16384, u + 1); }
    BAR_; LG0_;
    __builtin_amdgcn_s_setprio(1);
#pragma unroll
    for (int mi = 0; mi < 4; ++mi)
#pragma unroll
      for (int ni = 0; ni < 2; ++ni)
#pragma unroll
        for (int kk = 0; kk < 2; ++kk)
          acc[mi][2 + ni] = __builtin_amdgcn_mfma_f32_16x16x32_bf16(
              a[mi][kk], b[2 + ni][kk], acc[mi][2 + ni], 0, 0, 0);
    __builtin_amdgcn_s_setprio(0);
    BAR_;
    // ---- P3
#pragma unroll
    for (int kk = 0; kk < 2; ++kk)
#pragma unroll
      for (int mi = 0; mi < 4; ++mi)
        a[mi][kk] = *(const bf16x8*)&sm[cb + kk * 8192 + aoff + 2048 + mi * 512];
    if (u + 2 < NT) { STG_(gB[0][0], lA[0][0] + 16384, u + 2);
                      STG_(gB[0][1], lA[0][1] + 16384, u + 2); }
    BAR_; LG0_;
    __builtin_amdgcn_s_setprio(1);
#pragma unroll
    for (int mi = 0; mi < 4; ++mi)
#pragma unroll
      for (int ni = 0; ni < 2; ++ni)
#pragma unroll
        for (int kk = 0; kk < 2; ++kk)
          acc[4 + mi][2 + ni] = __builtin_amdgcn_mfma_f32_16x16x32_bf16(
              a[mi][kk], b[2 + ni][kk], acc[4 + mi][2 + ni], 0, 0, 0);
    __builtin_amdgcn_s_setprio(0);
    BAR_;
    // ---- P4
    if (u + 2 < NT) {
      STG_(gA[0][0], lA[0][0], u + 2); STG_(gA[0][1], lA[0][1], u + 2);
      asm volatile("s_waitcnt vmcnt(4)" ::: "memory");
    } else {
      asm volatile("s_waitcnt vmcnt(0)" ::: "memory");
    }
    BAR_;
    __builtin_amdgcn_s_setprio(1);
#pragma unroll
    for (int mi = 0; mi < 4; ++mi)
#pragma unroll
      for (int ni = 0; ni < 2; ++ni)
#pragma unroll
        for (int kk = 0; kk < 2; ++kk)
          acc[4 + mi][ni] = __builtin_amdgcn_mfma_f32_16x16x32_bf16(
              a[mi][kk], b[ni][kk], acc[4 + mi][ni], 0, 0, 0);
    __builtin_amdgcn_s_setprio(0);
    BAR_;
  }
#undef STG_
#undef BAR_
#undef LG0_
  // ---- store this slice's f32 partial (plain stores) ----
  int quad = lane >> 4, col = lane & 15;
  const size_t ss = (size_t)ntiles << 16;  // elems per slice (full matrix)
  float* Pp = P + (size_t)slice * ss;
#pragma unroll
  for (int mi = 0; mi < 8; ++mi)
#pragma unroll
    for (int ni = 0; ni < 4; ++ni)
#pragma unroll
      for (int rr = 0; rr < 4; ++rr)
        Pp[(size_t)(m0 + wr * 128 + mi * 16 + quad * 4 + rr) * N +
           n0 + wc * 64 + ni * 16 + col] = acc[mi][ni][rr];
  // ---- serial-K reduction: last block per tile sums slices 0..nslice-1 ----
  __threadfence();                      // release: drain + write back partials
  __syncthreads();
  __shared__ int windone;
  if (tid == 0)
    windone = (atomicAdd(&cnt[tile], 1) == nslice - 1) ? 1 : 0;
  __syncthreads();
  if (!windone) return;
  __threadfence();                      // acquire: invalidate stale cache lines
  int r0 = tid >> 2, c0 = (tid & 3) * 64;
  for (int pass = 0; pass < 2; ++pass) {
    size_t base = (size_t)(m0 + r0 + pass * 128) * N + n0 + c0;
    for (int i = 0; i < 64; i += 4) {
      float4 av = *(const float4*)&P[base + i];
      for (int s = 1; s < nslice; ++s) {
        float4 bv = *(const float4*)&P[(size_t)s * ss + base + i];
        av.x += bv.x; av.y += bv.y; av.z += bv.z; av.w += bv.w;
      }
      *(float4*)&Out[base + i] = av;
    }
  }
}

// ---- one launch: RoPE q,k [0,10240) + V transpose [10240,10496) + selU2 [10496,10560) --
__global__ __launch_bounds__(256)
void rv_k(u16* __restrict__ fused, const float* __restrict__ ct,
          const float* __restrict__ st, const int* __restrict__ pid,
          u16* __restrict__ vt, const double* __restrict__ partS,
          const float* __restrict__ Wkbk, double* __restrict__ partU) {
  __shared__ __align__(16) char rsm[33792];  // union: tile (9.2K) | buf+Sl (33K)
  int bid = blockIdx.x, t = threadIdx.x;
  if (bid < 10240) {  // RoPE
    int gid = bid * 256 + t;
    const int nq = B_ * QS * NH_ * 32;
    u16* x; int nh, g2;
    if (gid < nq) { x = fused;        nh = NH_;  g2 = gid; }
    else          { x = fused + 2048; nh = NKV_; g2 = gid - nq; }
    int per_row = nh * 32;
    int row = g2 / per_row;
    int rem = g2 - row * per_row;
    int h = rem >> 5, d = rem & 31;
    int pos = pid[row];
    float c = ct[pos * 64 + d];
    float s = st[pos * 64 + d];
    size_t base = (size_t)row * FS + h * 64 + d;
    float x0 = b2f(x[base]), x1 = b2f(x[base + 32]);
    x[base]      = f2b(x0 * c - x1 * s);
    x[base + 32] = f2b(x1 * c + x0 * s);
    return;
  }
  if (bid >= 10496) {  // selU2: U-partials = S @ Wkbk^T (double, red_d order)
    int l = bid - 10496;
    int jc = l & 3, yy = l >> 2;
    int b = yy >> 3;
    int c = (yy & 7) * 256 + t;
    double* buf = (double*)rsm;             // [32][128]
    double* Sl  = (double*)(rsm + 32768);   // [128]
    double a = 0.0;
    for (int pass = 0; pass < 4; ++pass) {
      int chb = pass * 32;
#pragma unroll
      for (int e = t; e < 4096; e += 256) {
        int ch = e >> 7, jj = e & 127;
        buf[ch * 128 + jj] = partS[(size_t)(chb + ch) * (B_ * 512) + b * 512 + jc * 128 + jj];
      }
      __syncthreads();
      if (t < 128) {
        for (int ch = 0; ch < 32; ++ch) a += buf[ch * 128 + t];   // red_d order
      }
      __syncthreads();
    }
    if (t < 128) Sl[t] = a;
    __syncthreads();
    const float* row = Wkbk + (size_t)c * 512 + jc * 128;
    double acc = 0.0;
    for (int j = 0; j < 128; j += 4) {
      float4 wv = *(const float4*)(row + j);
      acc += Sl[j] * (double)wv.x + Sl[j + 1] * (double)wv.y +
             Sl[j + 2] * (double)wv.z + Sl[j + 3] * (double)wv.w;
    }
    partU[(size_t)jc * (B_ * HID_) + b * HID_ + c] = acc;
    return;
  }
  // V transpose: vt[(b*8+g)*64+d][key] = v[key][g*64+d]
  int l = bid - 10240;
  int kt = l & 15, bg = l >> 4;
  int b = bg >> 3, g = bg & 7;
  u16* tile = (u16*)rsm;  // [64][72]
  {
    int kk = t >> 2, dc = (t & 3) * 16;
    const u16* src = fused + (size_t)(b * QS + kt * 64 + kk) * FS + 2560 + g * 64 + dc;
    *(uint4*)&tile[kk * 72 + dc]     = *(const uint4*)src;
    *(uint4*)&tile[kk * 72 + dc + 8] = *(const uint4*)(src + 8);
  }
  __syncthreads();
  {
    int d = t >> 2, kc = t & 3;
    __align__(16) u16 tmp[16];
#pragma unroll
    for (int i = 0; i < 16; ++i) tmp[i] = tile[(kc * 16 + i) * 72 + d];
    u16* dst = vt + ((size_t)bg * 64 + d) * 1024 + kt * 64 + kc * 16;
    *(uint4*)dst       = *(uint4*)&tmp[0];
    *(uint4*)(dst + 8) = *(uint4*)&tmp[8];
  }
}

// self with fused partU reduction (bit-identical jc order 0..3)
__global__ __launch_bounds__(256)
void self2_k(const double* __restrict__ partU, const float* __restrict__ kbin,
             double* __restrict__ part) {
  int n = blockIdx.x * 256 + threadIdx.x;
  int cc = blockIdx.y, b = blockIdx.z;
  int t = threadIdx.x;
  __shared__ double ul[256];
  {
    size_t ui = (size_t)b * HID_ + cc * 256 + t;
    double a = partU[ui];
    a += partU[(size_t)(B_ * HID_) + ui];
    a += partU[2 * (size_t)(B_ * HID_) + ui];
    a += partU[3 * (size_t)(B_ * HID_) + ui];
    ul[t] = a;
  }
  __syncthreads();
  const float* row = kbin + (size_t)(b * KBN_ + n) * HID_ + cc * 256;
  double acc = 0.0;
  for (int c = 0; c < 256; c += 4) {
    float4 kv = *(const float4*)(row + c);
    acc += ul[c] * (double)kv.x + ul[c + 1] * (double)kv.y +
           ul[c + 2] * (double)kv.z + ul[c + 3] * (double)kv.w;
  }
  part[(size_t)cc * (B_ * KBN_) + b * KBN_ + n] = acc;
}

// ---------------- fused partial-sum + parallel rank top-100 ----------------
__global__ __launch_bounds__(512)
void topk_rank_k(const double* __restrict__ partSel, int* __restrict__ idx) {
  int b = blockIdx.x, i = threadIdx.x;
  __shared__ float v[KBN_];
  double a = 0.0;
#pragma unroll
  for (int c = 0; c < 8; ++c) a += partSel[(size_t)c * (B_ * KBN_) + b * KBN_ + i];
  float vi = (float)a;
  v[i] = vi;
  __syncthreads();
  int rank = 0;
#pragma unroll 8
  for (int j = 0; j < KBN_; ++j) {
    float vj = v[j];
    rank += (vj > vi || (vj == vi && j < i)) ? 1 : 0;
  }
  if (rank < TOPK_) idx[b * TOPK_ + rank] = i;
}

// ---------------- top-k V gather: kbt[(b*8+g)*64+d][slot] ----------------
__global__ __launch_bounds__(256)
void kbgather_k(const u16* __restrict__ kbf, const int* __restrict__ topidx,
                u16* __restrict__ kbt) {
  int bg = blockIdx.x; int b = bg >> 3, g = bg & 7;
  int t = threadIdx.x;
  int d = t >> 2, s0 = (t & 3) * 32;
  __align__(16) u16 tmp[32];
#pragma unroll
  for (int i = 0; i < 32; ++i) {
    int slot = s0 + i;
    int n = topidx[b * TOPK_ + (slot < TOPK_ ? slot : TOPK_ - 1)];
    tmp[i] = kbf[(size_t)(b * KBN_ + n) * 1024 + 512 + g * 64 + d];
  }
  u16* dst = kbt + ((size_t)bg * 64 + d) * 128 + s0;
#pragma unroll
  for (int i = 0; i < 32; i += 8) *(uint4*)(dst + i) = *(uint4*)&tmp[i];
}

// ---------------- MFMA flash attention (fused-layout inputs) ----------------
__global__ __launch_bounds__(256)
void attn_mfma_k(const u16* __restrict__ fused, const u16* __restrict__ kbf,
                 const u16* __restrict__ vt, const u16* __restrict__ kbt,
                 const int* __restrict__ topidx, u16* __restrict__ ctx) {
  int bid = blockIdx.x;
  int raw = bid >> 6;            // 0..15
  int hb = bid & 63;
  int h = hb & 31, b = hb >> 5;
  int pg = raw >> 2, pp = raw & 3;
  int pbase = (pg >> 1) * 4 + pp;
  int qt = (pg & 1) ? (15 - pbase) : pbase;
  int g = h >> 2;
  int t = threadIdx.x, lane = t & 63, w = t >> 6;
  int quad = lane >> 4, col = lane & 15;
  __shared__ __align__(16) u16 ks[64 * 72];
  __shared__ __align__(16) u16 vst[64 * 64];
  __shared__ __align__(16) u16 ps[4][16 * 72];
  const float LOGADJ = 1.6331544f;  // ln(512/100)
  int q0 = qt * 64;

  int qrow_frag = q0 + w * 16 + col;
  bf16x8 aKB[2], aC[2];
#pragma unroll
  for (int kstep = 0; kstep < 2; ++kstep) {
    const u16* p1 = fused + (size_t)(b * QS + qrow_frag) * FS + 3072 + h * 64 + kstep * 32 + quad * 8;
    const u16* p2 = fused + (size_t)(b * QS + qrow_frag) * FS + 0    + h * 64 + kstep * 32 + quad * 8;
    uint4 x1 = *(const uint4*)p1, x2 = *(const uint4*)p2;
    const u16* u1 = (const u16*)&x1; const u16* u2 = (const u16*)&x2;
#pragma unroll
    for (int i = 0; i < 8; ++i) {
      aKB[kstep][i] = (bf16_t)(0.125f * b2f(u1[i]));
      aC[kstep][i]  = (bf16_t)(0.125f * b2f(u2[i]));
    }
  }

  float mrow[4] = {-1e30f, -1e30f, -1e30f, -1e30f};
  float lrow[4] = {0.f, 0.f, 0.f, 0.f};
  floatx4 acc[4];
#pragma unroll
  for (int nb = 0; nb < 4; ++nb) acc[nb] = (floatx4){0.f, 0.f, 0.f, 0.f};

  int sj = t >> 2, sdc = (t & 3) * 16, sc4 = t & 3;
  uint4 kr0, kr1, vr0, vr1;

#define LOADTILE(TT) do {                                                      \
    int _t = (TT);                                                             \
    const u16 *_src, *_vsrc;                                                   \
    if (_t < 2) {                                                              \
      int _slot = _t * 64 + sj;                                                \
      int _n = topidx[b * TOPK_ + (_slot < TOPK_ ? _slot : TOPK_ - 1)];        \
      _src = kbf + (size_t)(b * KBN_ + _n) * 1024 + g * 64 + sdc;              \
      _vsrc = kbt + ((size_t)(b * 8 + g) * 64 + sj) * 128 + _t * 64 + sc4 * 16;\
    } else {                                                                   \
      int _key = (_t - 2) * 64 + sj;                                           \
      _src = fused + (size_t)(b * QS + _key) * FS + 2048 + g * 64 + sdc;       \
      _vsrc = vt + ((size_t)(b * 8 + g) * 64 + sj) * 1024 + (_t - 2) * 64 + sc4 * 16; \
    }                                                                          \
    kr0 = *(const uint4*)_src;  kr1 = *(const uint4*)(_src + 8);               \
    vr0 = *(const uint4*)_vsrc; vr1 = *(const uint4*)(_vsrc + 8);              \
  } while (0)

  int ntiles = 2 + (q0 >> 6) + 1;
  LOADTILE(0);
  for (int tile = 0; tile < ntiles; ++tile) {
    __syncthreads();   // prior tile's LDS reads complete
    *(uint4*)&ks[sj * 72 + sdc]     = kr0;
    *(uint4*)&ks[sj * 72 + sdc + 8] = kr1;
    {
      int sw = sj & 7;
      *(uint4*)&vst[sj * 64 + ((2 * sc4)     ^ sw) * 8] = vr0;
      *(uint4*)&vst[sj * 64 + ((2 * sc4 + 1) ^ sw) * 8] = vr1;
    }
    if (tile + 1 < ntiles) LOADTILE(tile + 1);  // issue next-tile globals early
    __syncthreads();

    bf16x8 aq0 = (tile < 2) ? aKB[0] : aC[0];
    bf16x8 aq1 = (tile < 2) ? aKB[1] : aC[1];
    floatx4 s[4];
#pragma unroll
    for (int nb = 0; nb < 4; ++nb) {
      s[nb] = (floatx4){0.f, 0.f, 0.f, 0.f};
      bf16x8 b0 = *(bf16x8*)&ks[(nb * 16 + col) * 72 + quad * 8];
      bf16x8 b1 = *(bf16x8*)&ks[(nb * 16 + col) * 72 + 32 + quad * 8];
      s[nb] = __builtin_amdgcn_mfma_f32_16x16x32_bf16(aq0, b0, s[nb], 0, 0, 0);
      s[nb] = __builtin_amdgcn_mfma_f32_16x16x32_bf16(aq1, b1, s[nb], 0, 0, 0);
    }
    if (tile < 2) {
      if (tile == 0) {
#pragma unroll
        for (int nb = 0; nb < 4; ++nb)
#pragma unroll
          for (int rr = 0; rr < 4; ++rr) s[nb][rr] += LOGADJ;
      } else {
#pragma unroll
        for (int nb = 0; nb < 4; ++nb) {
          bool dead = (64 + nb * 16 + col) >= TOPK_;
#pragma unroll
          for (int rr = 0; rr < 4; ++rr)
            s[nb][rr] = dead ? -1e30f : (s[nb][rr] + LOGADJ);
        }
      }
    } else if (tile == ntiles - 1) {
      int kbase = (tile - 2) * 64;
#pragma unroll
      for (int nb = 0; nb < 4; ++nb) {
        int key = kbase + nb * 16 + col;
#pragma unroll
        for (int rr = 0; rr < 4; ++rr) {
          int qrow = q0 + w * 16 + quad * 4 + rr;
          if (key > qrow) s[nb][rr] = -1e30f;
        }
      }
    }
    float tm[4];
#pragma unroll
    for (int rr = 0; rr < 4; ++rr)
      tm[rr] = fmaxf(fmaxf(s[0][rr], s[1][rr]), fmaxf(s[2][rr], s[3][rr]));
#pragma unroll
    for (int off = 1; off < 16; off <<= 1)
#pragma unroll
      for (int rr = 0; rr < 4; ++rr)
        tm[rr] = fmaxf(tm[rr], __shfl_xor(tm[rr], off));
    float alpha[4], rs[4];
#pragma unroll
    for (int rr = 0; rr < 4; ++rr) {
      float mn = fmaxf(mrow[rr], tm[rr]);
      alpha[rr] = __expf(mrow[rr] - mn);
      mrow[rr] = mn;
      rs[rr] = 0.f;
    }
#pragma unroll
    for (int nb = 0; nb < 4; ++nb)
#pragma unroll
      for (int rr = 0; rr < 4; ++rr) {
        float ev = __expf(s[nb][rr] - mrow[rr]);
        rs[rr] += ev;
        ps[w][(quad * 4 + rr) * 72 + nb * 16 + col] = f2b(ev);
      }
#pragma unroll
    for (int off = 1; off < 16; off <<= 1)
#pragma unroll
      for (int rr = 0; rr < 4; ++rr)
        rs[rr] += __shfl_xor(rs[rr], off);
#pragma unroll
    for (int rr = 0; rr < 4; ++rr) lrow[rr] = lrow[rr] * alpha[rr] + rs[rr];
#pragma unroll
    for (int nb = 0; nb < 4; ++nb)
#pragma unroll
      for (int rr = 0; rr < 4; ++rr) acc[nb][rr] *= alpha[rr];

    bf16x8 pa0 = *(bf16x8*)&ps[w][col * 72 + quad * 8];
    bf16x8 pa1 = *(bf16x8*)&ps[w][col * 72 + 32 + quad * 8];
#pragma unroll
    for (int nb = 0; nb < 4; ++nb) {
      int d = nb * 16 + col;
      int sw = (d & 7) << 3;
      bf16x8 vb0 = *(bf16x8*)&vst[d * 64 + ((quad * 8) ^ sw)];
      bf16x8 vb1 = *(bf16x8*)&vst[d * 64 + ((32 + quad * 8) ^ sw)];
      acc[nb] = __builtin_amdgcn_mfma_f32_16x16x32_bf16(pa0, vb0, acc[nb], 0, 0, 0);
      acc[nb] = __builtin_amdgcn_mfma_f32_16x16x32_bf16(pa1, vb1, acc[nb], 0, 0, 0);
    }
  }
#undef LOADTILE
#pragma unroll
  for (int rr = 0; rr < 4; ++rr) {
    float inv = 1.f / lrow[rr];
    int qrow = q0 + w * 16 + quad * 4 + rr;
    size_t base = (size_t)(b * QS + qrow) * HID_ + h * 64;
#pragma unroll
    for (int nb = 0; nb < 4; ++nb)
      ctx[base + nb * 16 + col] = f2b(acc[nb][rr] * inv);
  }
}

// ---------------- host ----------------
extern "C" void kernel_launch(void* const* d_in, const int* in_sizes, int n_in,
                              void* d_out, int out_size, void* d_ws, size_t ws_size,
                              hipStream_t stream) {
  (void)in_sizes; (void)n_in; (void)out_size; (void)ws_size;
  const float* hs_f = (const float*)d_in[0];
  const float* kb_f = (const float*)d_in[1];
  const float* Wq   = (const float*)d_in[2];
  const float* Wk   = (const float*)d_in[3];
  const float* Wv   = (const float*)d_in[4];
  const float* Wo   = (const float*)d_in[5];
  const float* Wqn  = (const float*)d_in[6];
  const float* Wkbk = (const float*)d_in[7];
  const float* Wkbv = (const float*)d_in[8];
  const float* cosT = (const float*)d_in[9];
  const float* sinT = (const float*)d_in[10];
  const int*   pid  = (const int*)d_in[12];
  float* out = (float*)d_out;

  char* p = (char*)d_ws;
  u16* WT    = (u16*)p; p += (size_t)FS * 2048 * 2;       // 20 MB fused proj weights
  u16* WTkb  = (u16*)p; p += (size_t)1024 * 2048 * 2;     // 4 MB kb proj weights
  u16* WTo   = (u16*)p; p += (size_t)2048 * 2048 * 2;     // 8 MB out proj weights
  u16* fused = (u16*)p; p += (size_t)B_ * QS * FS * 2;    // 20 MB q|k|v|kbq
  u16* hs_b  = (u16*)p; p += (size_t)B_ * QS * HID_ * 2;  // 8 MB (ctx aliases later)
  u16* kb_b  = (u16*)p; p += (size_t)B_ * KBN_ * HID_ * 2;// 4 MB (v_t/kb_t alias later)
  u16* kbf   = (u16*)p; p += (size_t)B_ * KBN_ * 1024 * 2;// 2 MB kbk|kbv
  double* partH    = (double*)p; p += (size_t)64 * B_ * HID_ * 8;
  double* partS    = (double*)p; p += (size_t)128 * B_ * 512 * 8;
  double* partU    = (double*)p; p += (size_t)4 * B_ * HID_ * 8;
  double* partSel  = (double*)p; p += (size_t)8 * B_ * KBN_ * 8;
  float*  partKG   = (float*)p;  p += (size_t)4 * 2048 * 2048 * 4;  // 67 MB split-K partials
  int*    idx_ws   = (int*)p;    p += 1024;               // top-k indices (padded)
  int*    cnt_ws   = (int*)p;    p += 64 * 4;             // serial-K tile counters
  // aliases (lifetimes disjoint, stream-ordered):
  u16* ctx_ws = hs_b;                       // hs_b dead after gemm256j
  u16* v_t    = kb_b;                       // kb_b dead after gemm256j
  u16* kb_t   = kb_b + (size_t)B_ * 8 * 64 * 1024;

  dim3 blk(256);
  // zero serial-K tile counters (256 B, graph-capture-legal)
  hipMemsetAsync(cnt_ws, 0, 64 * sizeof(int), stream);
  // casts + all 7 weight transposes + hssum (one launch)
  tc7_k<<<dim3(22656), blk, 0, stream>>>(Wq, Wk, Wv, Wqn, Wkbk, Wkbv, Wo,
                                         WT, WTkb, WTo, hs_f, kb_f, hs_b, kb_b, partH);
  // fused-projection (160 tiles) + kb-projection (16 tiles) GEMM + selS2 filler (256)
  gemm256j<<<dim3(432), dim3(512), 0, stream>>>(hs_b, WT, fused, kb_b, WTkb, kbf, 2048,
                                                partH, Wqn, partS);
  // RoPE q,k + V transpose + selU2 (one launch)
  rv_k<<<dim3(10560), blk, 0, stream>>>(fused, cosT, sinT, pid, v_t,
                                        partS, Wkbk, partU);
  // selection tail
  self2_k<<<dim3(2, 8, B_), blk, 0, stream>>>(partU, kb_f, partSel);
  topk_rank_k<<<dim3(B_), dim3(512), 0, stream>>>(partSel, idx_ws);
  kbgather_k<<<dim3(B_ * 8), blk, 0, stream>>>(kbf, idx_ws, kb_t);
  // attention (1-D balanced grid; writes ctx = hs_b alias)
  attn_mfma_k<<<dim3(16 * NH_ * B_), blk, 0, stream>>>(fused, kbf, v_t, kb_t, idx_ws, ctx_ws);
  // output projection: split-K gemm256 (64 tiles x 4 slices of K=512),
  // serial-K fused reduction (fixed slice order == round-6 redp association)
  gemm256s<<<dim3(64 * 4), dim3(512), 0, stream>>>(ctx_ws, WTo, partKG, cnt_ws, out,
                                                   2048, 2048, 512, 64);
}

// Round 10
// 365.178 us; speedup vs baseline: 1.5080x; 1.5080x over previous
//
#include <hip/hip_runtime.h>

typedef unsigned short u16;
typedef unsigned int   u32;
typedef __bf16 bf16_t;
typedef bf16_t bf16x8 __attribute__((ext_vector_type(8)));
typedef float  floatx4 __attribute__((ext_vector_type(4)));

#define B_    2
#define QS    1024
#define HID_  2048
#define NH_   32
#define NKV_  8
#define HD_   64
#define KBN_  512
#define TOPK_ 100
#define FS    5120   // fused projection row stride: q|k|v|kbq = 0|2048|2560|3072

__device__ __forceinline__ float b2f(u16 u) {
  union { u32 i; float f; } x; x.i = ((u32)u) << 16; return x.f;
}
__device__ __forceinline__ u16 f2b(float f) {
  union { float f; u32 i; } x; x.f = f;
  u32 r = x.i + 0x7fffu + ((x.i >> 16) & 1u);
  return (u16)(r >> 16);
}
__device__ __forceinline__ void async16(const u16* g, u16* l) {
  __builtin_amdgcn_global_load_lds(
      (const __attribute__((address_space(1))) unsigned int*)g,
      (__attribute__((address_space(3))) unsigned int*)l, 16, 0, 0);
}

// ---- one launch: hs/kb casts + 7 weight transposes + hssum ----
// [0,4096) Wq | [4096,5120) Wk | [5120,6144) Wv | [6144,10240) Wqn
// [10240,11264) Wkbk | [11264,12288) Wkbv | [12288,16384) Wo->WTo
// [16384,20480) cast hs | [20480,22528) cast kb | [22528,22656) hssum
__global__ __launch_bounds__(256)
void tc7_k(const float* __restrict__ Wq, const float* __restrict__ Wk,
           const float* __restrict__ Wv, const float* __restrict__ Wqn,
           const float* __restrict__ Wkbk, const float* __restrict__ Wkbv,
           const float* __restrict__ Wo, u16* __restrict__ WT,
           u16* __restrict__ WTkb, u16* __restrict__ WTo,
           const float* __restrict__ hs, const float* __restrict__ kb,
           u16* __restrict__ hsb, u16* __restrict__ kbb,
           double* __restrict__ partH) {
  int id = blockIdx.x, t = threadIdx.x;
  if (id >= 22528) {  // hssum branch (partial column sums of hs, double)
    int l = id - 22528;
    int qc = l & 63, b = l >> 6;
    double a[8] = {0, 0, 0, 0, 0, 0, 0, 0};
    for (int qq = 0; qq < 16; ++qq) {
      const float* row = hs + (size_t)(b * QS + qc * 16 + qq) * HID_;
#pragma unroll
      for (int m = 0; m < 8; ++m) a[m] += (double)row[m * 256 + t];
    }
#pragma unroll
    for (int m = 0; m < 8; ++m)
      partH[(size_t)qc * (B_ * HID_) + b * HID_ + m * 256 + t] = a[m];
    return;
  }
  if (id >= 16384) {  // cast branch (no LDS, no sync)
    const float* x; u16* y; int j;
    if (id < 20480) { x = hs; y = hsb; j = (id - 16384) * 256 + t; }
    else            { x = kb; y = kbb; j = (id - 20480) * 256 + t; }
    float4 v = ((const float4*)x)[j];
    ((uint2*)y)[j] = make_uint2((u32)f2b(v.x) | ((u32)f2b(v.y) << 16),
                                (u32)f2b(v.z) | ((u32)f2b(v.w) << 16));
    return;
  }
  const float* W; u16* D; int N, bx, by;
  if (id < 4096)       { W = Wq;   D = WT;                        N = 2048; int l = id;         bx = l & 63; by = l >> 6; }
  else if (id < 5120)  { W = Wk;   D = WT + (size_t)2048 * 2048;  N = 512;  int l = id - 4096;  bx = l & 15; by = l >> 4; }
  else if (id < 6144)  { W = Wv;   D = WT + (size_t)2560 * 2048;  N = 512;  int l = id - 5120;  bx = l & 15; by = l >> 4; }
  else if (id < 10240) { W = Wqn;  D = WT + (size_t)3072 * 2048;  N = 2048; int l = id - 6144;  bx = l & 63; by = l >> 6; }
  else if (id < 11264) { W = Wkbk; D = WTkb;                      N = 512;  int l = id - 10240; bx = l & 15; by = l >> 4; }
  else if (id < 12288) { W = Wkbv; D = WTkb + (size_t)512 * 2048; N = 512;  int l = id - 11264; bx = l & 15; by = l >> 4; }
  else                 { W = Wo;   D = WTo;                       N = 2048; int l = id - 12288; bx = l & 63; by = l >> 6; }
  const int K = 2048;
  __shared__ float tile[32][33];
  int n0 = bx * 32, k0 = by * 32;
  int tx = t & 31, ty = t >> 5;
#pragma unroll
  for (int i = 0; i < 32; i += 8)
    tile[ty + i][tx] = W[(size_t)(k0 + ty + i) * N + n0 + tx];
  __syncthreads();
#pragma unroll
  for (int i = 0; i < 32; i += 8)
    D[(size_t)(n0 + ty + i) * K + k0 + tx] = f2b(tile[tx][ty + i]);
}

// ---- combined GEMM 256x256 8-phase: fused proj (160) + kb proj (16) + selS2 (256) --
// blocks [0,176) = GEMM (XCD-swizzled), [176,432) = selS2 filler on idle CUs.
__global__ __launch_bounds__(512, 2)
void gemm256j(const u16* __restrict__ A0, const u16* __restrict__ B0,
              u16* __restrict__ C0, const u16* __restrict__ A1,
              const u16* __restrict__ B1, u16* __restrict__ C1, int K,
              const double* __restrict__ partH, const float* __restrict__ Wqn,
              double* __restrict__ partS) {
  __shared__ __align__(16) u16 sm[65536];  // 128 KiB: [buf2][op2][kk2][256][32]
  const int tid = threadIdx.x, lane = tid & 63, w = tid >> 6;
  int orig = blockIdx.x;
  if (orig >= 176) {  // ---- selS2: S-partials = (col-sum hs) @ Wqn (double) ----
    int l = orig - 176;
    int chunk = l & 127, b = l >> 7, j = tid;
    double* tmpd = (double*)sm;        // 1024 doubles (aliased onto sm)
    double* hsl  = tmpd + 1024;        // 16 doubles
    int g = j >> 6, d = j & 63;
    int c0 = chunk * 16;
    {
      int ch = j >> 4, cc = j & 15;
      tmpd[ch * 16 + cc]        = partH[(size_t)ch * (B_ * HID_) + b * HID_ + c0 + cc];
      tmpd[(ch + 32) * 16 + cc] = partH[(size_t)(ch + 32) * (B_ * HID_) + b * HID_ + c0 + cc];
    }
    __syncthreads();
    if (j < 16) {
      double a = 0.0;
      for (int ch = 0; ch < 64; ++ch) a += tmpd[ch * 16 + j];   // red_d order
      hsl[j] = a;
    }
    __syncthreads();
    double acc = 0.0;
    for (int cc = 0; cc < 16; ++cc) {
      int c = c0 + cc;
      const float* wq = Wqn + (size_t)c * HID_ + g * 256 + d;
      acc += hsl[cc] *
             ((double)wq[0] + (double)wq[64] + (double)wq[128] + (double)wq[192]);
    }
    partS[(size_t)chunk * (B_ * 512) + b * 512 + j] = acc;
    return;
  }
  const int wr = w >> 2, wc = w & 3;
  int swz = (orig & 7) * 22 + (orig >> 3);  // XCD-contiguous, bijective (176=8*22)
  const u16 *A, *BT; u16* C; int CS, bx, by;
  if (swz < 160) { A = A0; BT = B0; C = C0; CS = FS;   bx = swz % 20; by = swz / 20; }
  else { int t2 = swz - 160; A = A1; BT = B1; C = C1; CS = 1024; bx = t2 & 3; by = t2 >> 2; }
  int m0 = by << 8, n0 = bx << 8;
  const int NT = K >> 6;

  int lr = lane >> 2;
  int colsw = ((lane & 3) * 8) ^ ((lane & 32) ? 16 : 0);  // inverse-swizzled source col
  const u16* gA[2][2]; const u16* gB[2][2];
  int lA[2][2];
#pragma unroll
  for (int h = 0; h < 2; ++h)
#pragma unroll
    for (int j = 0; j < 2; ++j) {
      int ij = 2 * w + j, kk = ij >> 3, rb = (ij & 7) * 16;
      gA[h][j] = A + (size_t)(m0 + h * 128 + rb + lr) * K + kk * 32 + colsw;
      gB[h][j] = BT + (size_t)(n0 + h * 128 + rb + lr) * K + kk * 32 + colsw;
      lA[h][j] = kk * 8192 + (h * 128 + rb) * 32;
    }
  int fsw = ((lane >> 4) * 8) ^ ((lane & 8) ? 16 : 0);
  int aoff = (wr * 128 + (lane & 15)) * 32 + fsw;
  int boff = 16384 + (wc * 64 + (lane & 15)) * 32 + fsw;

  floatx4 acc[8][4];
#pragma unroll
  for (int i = 0; i < 8; ++i)
#pragma unroll
    for (int j = 0; j < 4; ++j) acc[i][j] = (floatx4){0.f, 0.f, 0.f, 0.f};
  bf16x8 a[4][2], b[4][2];

#define STG_(g, l, u) async16((g) + (size_t)(u) * 64, &sm[(((u) & 1) << 15) + (l)])
#define BAR_ do { asm volatile("" ::: "memory"); __builtin_amdgcn_s_barrier(); \
                  asm volatile("" ::: "memory"); } while (0)
#define LG0_ do { asm volatile("s_waitcnt lgkmcnt(0)" ::: "memory"); \
                  __builtin_amdgcn_sched_barrier(0); } while (0)

  STG_(gA[0][0], lA[0][0], 0); STG_(gA[0][1], lA[0][1], 0);
  STG_(gA[1][0], lA[1][0], 0); STG_(gA[1][1], lA[1][1], 0);
  STG_(gB[0][0], lA[0][0] + 16384, 0); STG_(gB[0][1], lA[0][1] + 16384, 0);
  STG_(gB[1][0], lA[1][0] + 16384, 0); STG_(gB[1][1], lA[1][1] + 16384, 0);
  if (NT > 1) {
    STG_(gB[0][0], lA[0][0] + 16384, 1); STG_(gB[0][1], lA[0][1] + 16384, 1);
    STG_(gA[0][0], lA[0][0], 1); STG_(gA[0][1], lA[0][1], 1);
    asm volatile("s_waitcnt vmcnt(4)" ::: "memory");
  } else {
    asm volatile("s_waitcnt vmcnt(0)" ::: "memory");
  }
  BAR_;

  for (int u = 0; u < NT; ++u) {
    const int cb = (u & 1) << 15;
    // ---- P1
#pragma unroll
    for (int kk = 0; kk < 2; ++kk) {
#pragma unroll
      for (int mi = 0; mi < 4; ++mi)
        a[mi][kk] = *(const bf16x8*)&sm[cb + kk * 8192 + aoff + mi * 512];
#pragma unroll
      for (int ni = 0; ni < 2; ++ni)
        b[ni][kk] = *(const bf16x8*)&sm[cb + kk * 8192 + boff + ni * 512];
    }
    if (u + 1 < NT) { STG_(gA[1][0], lA[1][0], u + 1); STG_(gA[1][1], lA[1][1], u + 1); }
    BAR_; LG0_;
    __builtin_amdgcn_s_setprio(1);
#pragma unroll
    for (int mi = 0; mi < 4; ++mi)
#pragma unroll
      for (int ni = 0; ni < 2; ++ni)
#pragma unroll
        for (int kk = 0; kk < 2; ++kk)
          acc[mi][ni] = __builtin_amdgcn_mfma_f32_16x16x32_bf16(
              a[mi][kk], b[ni][kk], acc[mi][ni], 0, 0, 0);
    __builtin_amdgcn_s_setprio(0);
    BAR_;
    // ---- P2
#pragma unroll
    for (int kk = 0; kk < 2; ++kk)
#pragma unroll
      for (int ni = 0; ni < 2; ++ni)
        b[2 + ni][kk] = *(const bf16x8*)&sm[cb + kk * 8192 + boff + (2 + ni) * 512];
    if (u + 1 < NT) { STG_(gB[1][0], lA[1][0] + 16384, u + 1);
                      STG_(gB[1][1], lA[1][1] + 16384, u + 1); }
    BAR_; LG0_;
    __builtin_amdgcn_s_setprio(1);
#pragma unroll
    for (int mi = 0; mi < 4; ++mi)
#pragma unroll
      for (int ni = 0; ni < 2; ++ni)
#pragma unroll
        for (int kk = 0; kk < 2; ++kk)
          acc[mi][2 + ni] = __builtin_amdgcn_mfma_f32_16x16x32_bf16(
              a[mi][kk], b[2 + ni][kk], acc[mi][2 + ni], 0, 0, 0);
    __builtin_amdgcn_s_setprio(0);
    BAR_;
    // ---- P3
#pragma unroll
    for (int kk = 0; kk < 2; ++kk)
#pragma unroll
      for (int mi = 0; mi < 4; ++mi)
        a[mi][kk] = *(const bf16x8*)&sm[cb + kk * 8192 + aoff + 2048 + mi * 512];
    if (u + 2 < NT) { STG_(gB[0][0], lA[0][0] + 16384, u + 2);
                      STG_(gB[0][1], lA[0][1] + 16384, u + 2); }
    BAR_; LG0_;
    __builtin_amdgcn_s_setprio(1);
#pragma unroll
    for (int mi = 0; mi < 4; ++mi)
#pragma unroll
      for (int ni = 0; ni < 2; ++ni)
#pragma unroll
        for (int kk = 0; kk < 2; ++kk)
          acc[4 + mi][2 + ni] = __builtin_amdgcn_mfma_f32_16x16x32_bf16(
              a[mi][kk], b[2 + ni][kk], acc[4 + mi][2 + ni], 0, 0, 0);
    __builtin_amdgcn_s_setprio(0);
    BAR_;
    // ---- P4
    if (u + 2 < NT) {
      STG_(gA[0][0], lA[0][0], u + 2); STG_(gA[0][1], lA[0][1], u + 2);
      asm volatile("s_waitcnt vmcnt(4)" ::: "memory");
    } else {
      asm volatile("s_waitcnt vmcnt(0)" ::: "memory");
    }
    BAR_;
    __builtin_amdgcn_s_setprio(1);
#pragma unroll
    for (int mi = 0; mi < 4; ++mi)
#pragma unroll
      for (int ni = 0; ni < 2; ++ni)
#pragma unroll
        for (int kk = 0; kk < 2; ++kk)
          acc[4 + mi][ni] = __builtin_amdgcn_mfma_f32_16x16x32_bf16(
              a[mi][kk], b[ni][kk], acc[4 + mi][ni], 0, 0, 0);
    __builtin_amdgcn_s_setprio(0);
    BAR_;
  }
#undef STG_
#undef BAR_
#undef LG0_
  int quad = lane >> 4, col = lane & 15;
#pragma unroll
  for (int mi = 0; mi < 8; ++mi)
#pragma unroll
    for (int ni = 0; ni < 4; ++ni)
#pragma unroll
      for (int rr = 0; rr < 4; ++rr)
        C[(size_t)(m0 + wr * 128 + mi * 16 + quad * 4 + rr) * CS +
          n0 + wc * 64 + ni * 16 + col] = f2b(acc[mi][ni][rr]);
}

// ---------------- split-K GEMM 256x256 8-phase, f32 partial output ----------------
// grid = ntiles * nslice blocks. tile = id % ntiles (XCD-swizzled), slice = id / ntiles.
__global__ __launch_bounds__(512, 2)
void gemm256s(const u16* __restrict__ A, const u16* __restrict__ BT,
              float* __restrict__ P, int N, int LDK, int Kl, int ntiles) {
  __shared__ __align__(16) u16 sm[65536];  // 128 KiB
  const int tid = threadIdx.x, lane = tid & 63, w = tid >> 6;
  const int wr = w >> 2, wc = w & 3;
  const int nbx = N >> 8;
  int nwg = gridDim.x, orig = blockIdx.x, swz = orig;
  if ((nwg & 7) == 0) swz = (orig & 7) * (nwg >> 3) + (orig >> 3);  // XCD-contig
  int tile = swz % ntiles, slice = swz / ntiles;
  int bx = tile % nbx, by = tile / nbx;
  int m0 = by << 8, n0 = bx << 8;
  const int NT = Kl >> 6;
  const u16* As = A + (size_t)slice * Kl;
  const u16* Bs = BT + (size_t)slice * Kl;

  int lr = lane >> 2;
  int colsw = ((lane & 3) * 8) ^ ((lane & 32) ? 16 : 0);
  const u16* gA[2][2]; const u16* gB[2][2];
  int lA[2][2];
#pragma unroll
  for (int h = 0; h < 2; ++h)
#pragma unroll
    for (int j = 0; j < 2; ++j) {
      int ij = 2 * w + j, kk = ij >> 3, rb = (ij & 7) * 16;
      gA[h][j] = As + (size_t)(m0 + h * 128 + rb + lr) * LDK + kk * 32 + colsw;
      gB[h][j] = Bs + (size_t)(n0 + h * 128 + rb + lr) * LDK + kk * 32 + colsw;
      lA[h][j] = kk * 8192 + (h * 128 + rb) * 32;
    }
  int fsw = ((lane >> 4) * 8) ^ ((lane & 8) ? 16 : 0);
  int aoff = (wr * 128 + (lane & 15)) * 32 + fsw;
  int boff = 16384 + (wc * 64 + (lane & 15)) * 32 + fsw;

  floatx4 acc[8][4];
#pragma unroll
  for (int i = 0; i < 8; ++i)
#pragma unroll
    for (int j = 0; j < 4; ++j) acc[i][j] = (floatx4){0.f, 0.f, 0.f, 0.f};
  bf16x8 a[4][2], b[4][2];

#define STG_(g, l, u) async16((g) + (size_t)(u) * 64, &sm[(((u) & 1) << 15) + (l)])
#define BAR_ do { asm volatile("" ::: "memory"); __builtin_amdgcn_s_barrier(); \
                  asm volatile("" ::: "memory"); } while (0)
#define LG0_ do { asm volatile("s_waitcnt lgkmcnt(0)" ::: "memory"); \
                  __builtin_amdgcn_sched_barrier(0); } while (0)

  STG_(gA[0][0], lA[0][0], 0); STG_(gA[0][1], lA[0][1], 0);
  STG_(gA[1][0], lA[1][0], 0); STG_(gA[1][1], lA[1][1], 0);
  STG_(gB[0][0], lA[0][0] + 16384, 0); STG_(gB[0][1], lA[0][1] + 16384, 0);
  STG_(gB[1][0], lA[1][0] + 16384, 0); STG_(gB[1][1], lA[1][1] + 16384, 0);
  if (NT > 1) {
    STG_(gB[0][0], lA[0][0] + 16384, 1); STG_(gB[0][1], lA[0][1] + 16384, 1);
    STG_(gA[0][0], lA[0][0], 1); STG_(gA[0][1], lA[0][1], 1);
    asm volatile("s_waitcnt vmcnt(4)" ::: "memory");
  } else {
    asm volatile("s_waitcnt vmcnt(0)" ::: "memory");
  }
  BAR_;

  for (int u = 0; u < NT; ++u) {
    const int cb = (u & 1) << 15;
    // ---- P1
#pragma unroll
    for (int kk = 0; kk < 2; ++kk) {
#pragma unroll
      for (int mi = 0; mi < 4; ++mi)
        a[mi][kk] = *(const bf16x8*)&sm[cb + kk * 8192 + aoff + mi * 512];
#pragma unroll
      for (int ni = 0; ni < 2; ++ni)
        b[ni][kk] = *(const bf16x8*)&sm[cb + kk * 8192 + boff + ni * 512];
    }
    if (u + 1 < NT) { STG_(gA[1][0], lA[1][0], u + 1); STG_(gA[1][1], lA[1][1], u + 1); }
    BAR_; LG0_;
    __builtin_amdgcn_s_setprio(1);
#pragma unroll
    for (int mi = 0; mi < 4; ++mi)
#pragma unroll
      for (int ni = 0; ni < 2; ++ni)
#pragma unroll
        for (int kk = 0; kk < 2; ++kk)
          acc[mi][ni] = __builtin_amdgcn_mfma_f32_16x16x32_bf16(
              a[mi][kk], b[ni][kk], acc[mi][ni], 0, 0, 0);
    __builtin_amdgcn_s_setprio(0);
    BAR_;
    // ---- P2
#pragma unroll
    for (int kk = 0; kk < 2; ++kk)
#pragma unroll
      for (int ni = 0; ni < 2; ++ni)
        b[2 + ni][kk] = *(const bf16x8*)&sm[cb + kk * 8192 + boff + (2 + ni) * 512];
    if (u + 1 < NT) { STG_(gB[1][0], lA[1][0] + 16384, u + 1);
                      STG_(gB[1][1], lA[1][1] + 16384, u + 1); }
    BAR_; LG0_;
    __builtin_amdgcn_s_setprio(1);
#pragma unroll
    for (int mi = 0; mi < 4; ++mi)
#pragma unroll
      for (int ni = 0; ni < 2; ++ni)
#pragma unroll
        for (int kk = 0; kk < 2; ++kk)
          acc[mi][2 + ni] = __builtin_amdgcn_mfma_f32_16x16x32_bf16(
              a[mi][kk], b[2 + ni][kk], acc[mi][2 + ni], 0, 0, 0);
    __builtin_amdgcn_s_setprio(0);
    BAR_;
    // ---- P3
#pragma unroll
    for (int kk = 0; kk < 2; ++kk)
#pragma unroll
      for (int mi = 0; mi < 4; ++mi)
        a[mi][kk] = *(const bf16x8*)&sm[cb + kk * 8192 + aoff + 2048 + mi * 512];
    if (u + 2 < NT) { STG_(gB[0][0], lA[0][0] + 16384, u + 2);
                      STG_(gB[0][1], lA[0][1] + 16384, u + 2); }
    BAR_; LG0_;
    __builtin_amdgcn_s_setprio(1);
#pragma unroll
    for (int mi = 0; mi < 4; ++mi)
#pragma unroll
      for (int ni = 0; ni < 2; ++ni)
#pragma unroll
        for (int kk = 0; kk < 2; ++kk)
          acc[4 + mi][2 + ni] = __builtin_amdgcn_mfma_f32_16x16x32_bf16(
              a[mi][kk], b[2 + ni][kk], acc[4 + mi][2 + ni], 0, 0, 0);
    __builtin_amdgcn_s_setprio(0);
    BAR_;
    // ---- P4
    if (u + 2 < NT) {
      STG_(gA[0][0], lA[0][0], u + 2); STG_(gA[0][1], lA[0][1], u + 2);
      asm volatile("s_waitcnt vmcnt(4)" ::: "memory");
    } else {
      asm volatile("s_waitcnt vmcnt(0)" ::: "memory");
    }
    BAR_;
    __builtin_amdgcn_s_setprio(1);
#pragma unroll
    for (int mi = 0; mi < 4; ++mi)
#pragma unroll
      for (int ni = 0; ni < 2; ++ni)
#pragma unroll
        for (int kk = 0; kk < 2; ++kk)
          acc[4 + mi][ni] = __builtin_amdgcn_mfma_f32_16x16x32_bf16(
              a[mi][kk], b[ni][kk], acc[4 + mi][ni], 0, 0, 0);
    __builtin_amdgcn_s_setprio(0);
    BAR_;
  }
#undef STG_
#undef BAR_
#undef LG0_
  int quad = lane >> 4, col = lane & 15;
  float* Pp = P + (size_t)slice * ((size_t)ntiles << 16);
#pragma unroll
  for (int mi = 0; mi < 8; ++mi)
#pragma unroll
    for (int ni = 0; ni < 4; ++ni)
#pragma unroll
      for (int rr = 0; rr < 4; ++rr)
        Pp[(size_t)(m0 + wr * 128 + mi * 16 + quad * 4 + rr) * N +
           n0 + wc * 64 + ni * 16 + col] = acc[mi][ni][rr];
}

// ---------------- split-K partial reduction: out = sum_s P[s] (f32 out) ----------------
__global__ __launch_bounds__(256)
void redp_k(const float* __restrict__ P, float* __restrict__ out, int nslice, int len4) {
  int i = blockIdx.x * 256 + threadIdx.x;
  if (i >= len4) return;
  float4 a = ((const float4*)P)[i];
  for (int s = 1; s < nslice; ++s) {
    float4 b = ((const float4*)P)[(size_t)s * len4 + i];
    a.x += b.x; a.y += b.y; a.z += b.z; a.w += b.w;
  }
  ((float4*)out)[i] = a;
}

// ---- one launch: RoPE q,k [0,10240) + V transpose [10240,10496) + selU2 [10496,10560) --
__global__ __launch_bounds__(256)
void rv_k(u16* __restrict__ fused, const float* __restrict__ ct,
          const float* __restrict__ st, const int* __restrict__ pid,
          u16* __restrict__ vt, const double* __restrict__ partS,
          const float* __restrict__ Wkbk, double* __restrict__ partU) {
  __shared__ __align__(16) char rsm[33792];  // union: tile (9.2K) | buf+Sl (33K)
  int bid = blockIdx.x, t = threadIdx.x;
  if (bid < 10240) {  // RoPE
    int gid = bid * 256 + t;
    const int nq = B_ * QS * NH_ * 32;
    u16* x; int nh, g2;
    if (gid < nq) { x = fused;        nh = NH_;  g2 = gid; }
    else          { x = fused + 2048; nh = NKV_; g2 = gid - nq; }
    int per_row = nh * 32;
    int row = g2 / per_row;
    int rem = g2 - row * per_row;
    int h = rem >> 5, d = rem & 31;
    int pos = pid[row];
    float c = ct[pos * 64 + d];
    float s = st[pos * 64 + d];
    size_t base = (size_t)row * FS + h * 64 + d;
    float x0 = b2f(x[base]), x1 = b2f(x[base + 32]);
    x[base]      = f2b(x0 * c - x1 * s);
    x[base + 32] = f2b(x1 * c + x0 * s);
    return;
  }
  if (bid >= 10496) {  // selU2: U-partials = S @ Wkbk^T (double, red_d order)
    int l = bid - 10496;
    int jc = l & 3, yy = l >> 2;
    int b = yy >> 3;
    int c = (yy & 7) * 256 + t;
    double* buf = (double*)rsm;             // [32][128]
    double* Sl  = (double*)(rsm + 32768);   // [128]
    double a = 0.0;
    for (int pass = 0; pass < 4; ++pass) {
      int chb = pass * 32;
#pragma unroll
      for (int e = t; e < 4096; e += 256) {
        int ch = e >> 7, jj = e & 127;
        buf[ch * 128 + jj] = partS[(size_t)(chb + ch) * (B_ * 512) + b * 512 + jc * 128 + jj];
      }
      __syncthreads();
      if (t < 128) {
        for (int ch = 0; ch < 32; ++ch) a += buf[ch * 128 + t];   // red_d order
      }
      __syncthreads();
    }
    if (t < 128) Sl[t] = a;
    __syncthreads();
    const float* row = Wkbk + (size_t)c * 512 + jc * 128;
    double acc = 0.0;
    for (int j = 0; j < 128; j += 4) {
      float4 wv = *(const float4*)(row + j);
      acc += Sl[j] * (double)wv.x + Sl[j + 1] * (double)wv.y +
             Sl[j + 2] * (double)wv.z + Sl[j + 3] * (double)wv.w;
    }
    partU[(size_t)jc * (B_ * HID_) + b * HID_ + c] = acc;
    return;
  }
  // V transpose: vt[(b*8+g)*64+d][key] = v[key][g*64+d]
  int l = bid - 10240;
  int kt = l & 15, bg = l >> 4;
  int b = bg >> 3, g = bg & 7;
  u16* tile = (u16*)rsm;  // [64][72]
  {
    int kk = t >> 2, dc = (t & 3) * 16;
    const u16* src = fused + (size_t)(b * QS + kt * 64 + kk) * FS + 2560 + g * 64 + dc;
    *(uint4*)&tile[kk * 72 + dc]     = *(const uint4*)src;
    *(uint4*)&tile[kk * 72 + dc + 8] = *(const uint4*)(src + 8);
  }
  __syncthreads();
  {
    int d = t >> 2, kc = t & 3;
    __align__(16) u16 tmp[16];
#pragma unroll
    for (int i = 0; i < 16; ++i) tmp[i] = tile[(kc * 16 + i) * 72 + d];
    u16* dst = vt + ((size_t)bg * 64 + d) * 1024 + kt * 64 + kc * 16;
    *(uint4*)dst       = *(uint4*)&tmp[0];
    *(uint4*)(dst + 8) = *(uint4*)&tmp[8];
  }
}

// self with fused partU reduction (bit-identical jc order 0..3)
__global__ __launch_bounds__(256)
void self2_k(const double* __restrict__ partU, const float* __restrict__ kbin,
             double* __restrict__ part) {
  int n = blockIdx.x * 256 + threadIdx.x;
  int cc = blockIdx.y, b = blockIdx.z;
  int t = threadIdx.x;
  __shared__ double ul[256];
  {
    size_t ui = (size_t)b * HID_ + cc * 256 + t;
    double a = partU[ui];
    a += partU[(size_t)(B_ * HID_) + ui];
    a += partU[2 * (size_t)(B_ * HID_) + ui];
    a += partU[3 * (size_t)(B_ * HID_) + ui];
    ul[t] = a;
  }
  __syncthreads();
  const float* row = kbin + (size_t)(b * KBN_ + n) * HID_ + cc * 256;
  double acc = 0.0;
  for (int c = 0; c < 256; c += 4) {
    float4 kv = *(const float4*)(row + c);
    acc += ul[c] * (double)kv.x + ul[c + 1] * (double)kv.y +
           ul[c + 2] * (double)kv.z + ul[c + 3] * (double)kv.w;
  }
  part[(size_t)cc * (B_ * KBN_) + b * KBN_ + n] = acc;
}

// ---------------- fused partial-sum + parallel rank top-100 ----------------
__global__ __launch_bounds__(512)
void topk_rank_k(const double* __restrict__ partSel, int* __restrict__ idx) {
  int b = blockIdx.x, i = threadIdx.x;
  __shared__ float v[KBN_];
  double a = 0.0;
#pragma unroll
  for (int c = 0; c < 8; ++c) a += partSel[(size_t)c * (B_ * KBN_) + b * KBN_ + i];
  float vi = (float)a;
  v[i] = vi;
  __syncthreads();
  int rank = 0;
#pragma unroll 8
  for (int j = 0; j < KBN_; ++j) {
    float vj = v[j];
    rank += (vj > vi || (vj == vi && j < i)) ? 1 : 0;
  }
  if (rank < TOPK_) idx[b * TOPK_ + rank] = i;
}

// ---------------- top-k V gather: kbt[(b*8+g)*64+d][slot] ----------------
__global__ __launch_bounds__(256)
void kbgather_k(const u16* __restrict__ kbf, const int* __restrict__ topidx,
                u16* __restrict__ kbt) {
  int bg = blockIdx.x; int b = bg >> 3, g = bg & 7;
  int t = threadIdx.x;
  int d = t >> 2, s0 = (t & 3) * 32;
  __align__(16) u16 tmp[32];
#pragma unroll
  for (int i = 0; i < 32; ++i) {
    int slot = s0 + i;
    int n = topidx[b * TOPK_ + (slot < TOPK_ ? slot : TOPK_ - 1)];
    tmp[i] = kbf[(size_t)(b * KBN_ + n) * 1024 + 512 + g * 64 + d];
  }
  u16* dst = kbt + ((size_t)bg * 64 + d) * 128 + s0;
#pragma unroll
  for (int i = 0; i < 32; i += 8) *(uint4*)(dst + i) = *(uint4*)&tmp[i];
}

// ---------------- MFMA flash attention (fused-layout inputs) ----------------
__global__ __launch_bounds__(256)
void attn_mfma_k(const u16* __restrict__ fused, const u16* __restrict__ kbf,
                 const u16* __restrict__ vt, const u16* __restrict__ kbt,
                 const int* __restrict__ topidx, u16* __restrict__ ctx) {
  int bid = blockIdx.x;
  int raw = bid >> 6;            // 0..15
  int hb = bid & 63;
  int h = hb & 31, b = hb >> 5;
  int pg = raw >> 2, pp = raw & 3;
  int pbase = (pg >> 1) * 4 + pp;
  int qt = (pg & 1) ? (15 - pbase) : pbase;
  int g = h >> 2;
  int t = threadIdx.x, lane = t & 63, w = t >> 6;
  int quad = lane >> 4, col = lane & 15;
  __shared__ __align__(16) u16 ks[64 * 72];
  __shared__ __align__(16) u16 vst[64 * 64];
  __shared__ __align__(16) u16 ps[4][16 * 72];
  const float LOGADJ = 1.6331544f;  // ln(512/100)
  int q0 = qt * 64;

  int qrow_frag = q0 + w * 16 + col;
  bf16x8 aKB[2], aC[2];
#pragma unroll
  for (int kstep = 0; kstep < 2; ++kstep) {
    const u16* p1 = fused + (size_t)(b * QS + qrow_frag) * FS + 3072 + h * 64 + kstep * 32 + quad * 8;
    const u16* p2 = fused + (size_t)(b * QS + qrow_frag) * FS + 0    + h * 64 + kstep * 32 + quad * 8;
    uint4 x1 = *(const uint4*)p1, x2 = *(const uint4*)p2;
    const u16* u1 = (const u16*)&x1; const u16* u2 = (const u16*)&x2;
#pragma unroll
    for (int i = 0; i < 8; ++i) {
      aKB[kstep][i] = (bf16_t)(0.125f * b2f(u1[i]));
      aC[kstep][i]  = (bf16_t)(0.125f * b2f(u2[i]));
    }
  }

  float mrow[4] = {-1e30f, -1e30f, -1e30f, -1e30f};
  float lrow[4] = {0.f, 0.f, 0.f, 0.f};
  floatx4 acc[4];
#pragma unroll
  for (int nb = 0; nb < 4; ++nb) acc[nb] = (floatx4){0.f, 0.f, 0.f, 0.f};

  int sj = t >> 2, sdc = (t & 3) * 16, sc4 = t & 3;
  uint4 kr0, kr1, vr0, vr1;

#define LOADTILE(TT) do {                                                      \
    int _t = (TT);                                                             \
    const u16 *_src, *_vsrc;                                                   \
    if (_t < 2) {                                                              \
      int _slot = _t * 64 + sj;                                                \
      int _n = topidx[b * TOPK_ + (_slot < TOPK_ ? _slot : TOPK_ - 1)];        \
      _src = kbf + (size_t)(b * KBN_ + _n) * 1024 + g * 64 + sdc;              \
      _vsrc = kbt + ((size_t)(b * 8 + g) * 64 + sj) * 128 + _t * 64 + sc4 * 16;\
    } else {                                                                   \
      int _key = (_t - 2) * 64 + sj;                                           \
      _src = fused + (size_t)(b * QS + _key) * FS + 2048 + g * 64 + sdc;       \
      _vsrc = vt + ((size_t)(b * 8 + g) * 64 + sj) * 1024 + (_t - 2) * 64 + sc4 * 16; \
    }                                                                          \
    kr0 = *(const uint4*)_src;  kr1 = *(const uint4*)(_src + 8);               \
    vr0 = *(const uint4*)_vsrc; vr1 = *(const uint4*)(_vsrc + 8);              \
  } while (0)

  int ntiles = 2 + (q0 >> 6) + 1;
  LOADTILE(0);
  for (int tile = 0; tile < ntiles; ++tile) {
    __syncthreads();   // prior tile's LDS reads complete
    *(uint4*)&ks[sj * 72 + sdc]     = kr0;
    *(uint4*)&ks[sj * 72 + sdc + 8] = kr1;
    {
      int sw = sj & 7;
      *(uint4*)&vst[sj * 64 + ((2 * sc4)     ^ sw) * 8] = vr0;
      *(uint4*)&vst[sj * 64 + ((2 * sc4 + 1) ^ sw) * 8] = vr1;
    }
    if (tile + 1 < ntiles) LOADTILE(tile + 1);  // issue next-tile globals early
    __syncthreads();

    bf16x8 aq0 = (tile < 2) ? aKB[0] : aC[0];
    bf16x8 aq1 = (tile < 2) ? aKB[1] : aC[1];
    floatx4 s[4];
#pragma unroll
    for (int nb = 0; nb < 4; ++nb) {
      s[nb] = (floatx4){0.f, 0.f, 0.f, 0.f};
      bf16x8 b0 = *(bf16x8*)&ks[(nb * 16 + col) * 72 + quad * 8];
      bf16x8 b1 = *(bf16x8*)&ks[(nb * 16 + col) * 72 + 32 + quad * 8];
      s[nb] = __builtin_amdgcn_mfma_f32_16x16x32_bf16(aq0, b0, s[nb], 0, 0, 0);
      s[nb] = __builtin_amdgcn_mfma_f32_16x16x32_bf16(aq1, b1, s[nb], 0, 0, 0);
    }
    if (tile < 2) {
      if (tile == 0) {
#pragma unroll
        for (int nb = 0; nb < 4; ++nb)
#pragma unroll
          for (int rr = 0; rr < 4; ++rr) s[nb][rr] += LOGADJ;
      } else {
#pragma unroll
        for (int nb = 0; nb < 4; ++nb) {
          bool dead = (64 + nb * 16 + col) >= TOPK_;
#pragma unroll
          for (int rr = 0; rr < 4; ++rr)
            s[nb][rr] = dead ? -1e30f : (s[nb][rr] + LOGADJ);
        }
      }
    } else if (tile == ntiles - 1) {
      int kbase = (tile - 2) * 64;
#pragma unroll
      for (int nb = 0; nb < 4; ++nb) {
        int key = kbase + nb * 16 + col;
#pragma unroll
        for (int rr = 0; rr < 4; ++rr) {
          int qrow = q0 + w * 16 + quad * 4 + rr;
          if (key > qrow) s[nb][rr] = -1e30f;
        }
      }
    }
    float tm[4];
#pragma unroll
    for (int rr = 0; rr < 4; ++rr)
      tm[rr] = fmaxf(fmaxf(s[0][rr], s[1][rr]), fmaxf(s[2][rr], s[3][rr]));
#pragma unroll
    for (int off = 1; off < 16; off <<= 1)
#pragma unroll
      for (int rr = 0; rr < 4; ++rr)
        tm[rr] = fmaxf(tm[rr], __shfl_xor(tm[rr], off));
    float alpha[4], rs[4];
#pragma unroll
    for (int rr = 0; rr < 4; ++rr) {
      float mn = fmaxf(mrow[rr], tm[rr]);
      alpha[rr] = __expf(mrow[rr] - mn);
      mrow[rr] = mn;
      rs[rr] = 0.f;
    }
#pragma unroll
    for (int nb = 0; nb < 4; ++nb)
#pragma unroll
      for (int rr = 0; rr < 4; ++rr) {
        float ev = __expf(s[nb][rr] - mrow[rr]);
        rs[rr] += ev;
        ps[w][(quad * 4 + rr) * 72 + nb * 16 + col] = f2b(ev);
      }
#pragma unroll
    for (int off = 1; off < 16; off <<= 1)
#pragma unroll
      for (int rr = 0; rr < 4; ++rr)
        rs[rr] += __shfl_xor(rs[rr], off);
#pragma unroll
    for (int rr = 0; rr < 4; ++rr) lrow[rr] = lrow[rr] * alpha[rr] + rs[rr];
#pragma unroll
    for (int nb = 0; nb < 4; ++nb)
#pragma unroll
      for (int rr = 0; rr < 4; ++rr) acc[nb][rr] *= alpha[rr];

    bf16x8 pa0 = *(bf16x8*)&ps[w][col * 72 + quad * 8];
    bf16x8 pa1 = *(bf16x8*)&ps[w][col * 72 + 32 + quad * 8];
#pragma unroll
    for (int nb = 0; nb < 4; ++nb) {
      int d = nb * 16 + col;
      int sw = (d & 7) << 3;
      bf16x8 vb0 = *(bf16x8*)&vst[d * 64 + ((quad * 8) ^ sw)];
      bf16x8 vb1 = *(bf16x8*)&vst[d * 64 + ((32 + quad * 8) ^ sw)];
      acc[nb] = __builtin_amdgcn_mfma_f32_16x16x32_bf16(pa0, vb0, acc[nb], 0, 0, 0);
      acc[nb] = __builtin_amdgcn_mfma_f32_16x16x32_bf16(pa1, vb1, acc[nb], 0, 0, 0);
    }
  }
#undef LOADTILE
#pragma unroll
  for (int rr = 0; rr < 4; ++rr) {
    float inv = 1.f / lrow[rr];
    int qrow = q0 + w * 16 + quad * 4 + rr;
    size_t base = (size_t)(b * QS + qrow) * HID_ + h * 64;
#pragma unroll
    for (int nb = 0; nb < 4; ++nb)
      ctx[base + nb * 16 + col] = f2b(acc[nb][rr] * inv);
  }
}

// ---------------- host ----------------
extern "C" void kernel_launch(void* const* d_in, const int* in_sizes, int n_in,
                              void* d_out, int out_size, void* d_ws, size_t ws_size,
                              hipStream_t stream) {
  (void)in_sizes; (void)n_in; (void)out_size; (void)ws_size;
  const float* hs_f = (const float*)d_in[0];
  const float* kb_f = (const float*)d_in[1];
  const float* Wq   = (const float*)d_in[2];
  const float* Wk   = (const float*)d_in[3];
  const float* Wv   = (const float*)d_in[4];
  const float* Wo   = (const float*)d_in[5];
  const float* Wqn  = (const float*)d_in[6];
  const float* Wkbk = (const float*)d_in[7];
  const float* Wkbv = (const float*)d_in[8];
  const float* cosT = (const float*)d_in[9];
  const float* sinT = (const float*)d_in[10];
  const int*   pid  = (const int*)d_in[12];
  float* out = (float*)d_out;

  char* p = (char*)d_ws;
  u16* WT    = (u16*)p; p += (size_t)FS * 2048 * 2;       // 20 MB fused proj weights
  u16* WTkb  = (u16*)p; p += (size_t)1024 * 2048 * 2;     // 4 MB kb proj weights
  u16* WTo   = (u16*)p; p += (size_t)2048 * 2048 * 2;     // 8 MB out proj weights
  u16* fused = (u16*)p; p += (size_t)B_ * QS * FS * 2;    // 20 MB q|k|v|kbq
  u16* hs_b  = (u16*)p; p += (size_t)B_ * QS * HID_ * 2;  // 8 MB (ctx aliases later)
  u16* kb_b  = (u16*)p; p += (size_t)B_ * KBN_ * HID_ * 2;// 4 MB (v_t/kb_t alias later)
  u16* kbf   = (u16*)p; p += (size_t)B_ * KBN_ * 1024 * 2;// 2 MB kbk|kbv
  double* partH    = (double*)p; p += (size_t)64 * B_ * HID_ * 8;
  double* partS    = (double*)p; p += (size_t)128 * B_ * 512 * 8;
  double* partU    = (double*)p; p += (size_t)4 * B_ * HID_ * 8;
  double* partSel  = (double*)p; p += (size_t)8 * B_ * KBN_ * 8;
  float*  partKG   = (float*)p;  p += (size_t)4 * 2048 * 2048 * 4;  // 67 MB split-K partials
  int*    idx_ws   = (int*)p;    p += 1024;               // top-k indices (padded)
  // aliases (lifetimes disjoint, stream-ordered):
  u16* ctx_ws = hs_b;                       // hs_b dead after gemm256j
  u16* v_t    = kb_b;                       // kb_b dead after gemm256j
  u16* kb_t   = kb_b + (size_t)B_ * 8 * 64 * 1024;

  dim3 blk(256);
  // casts + all 7 weight transposes + hssum (one launch)
  tc7_k<<<dim3(22656), blk, 0, stream>>>(Wq, Wk, Wv, Wqn, Wkbk, Wkbv, Wo,
                                         WT, WTkb, WTo, hs_f, kb_f, hs_b, kb_b, partH);
  // fused-projection (160 tiles) + kb-projection (16 tiles) GEMM + selS2 filler (256)
  gemm256j<<<dim3(432), dim3(512), 0, stream>>>(hs_b, WT, fused, kb_b, WTkb, kbf, 2048,
                                                partH, Wqn, partS);
  // RoPE q,k + V transpose + selU2 (one launch)
  rv_k<<<dim3(10560), blk, 0, stream>>>(fused, cosT, sinT, pid, v_t,
                                        partS, Wkbk, partU);
  // selection tail
  self2_k<<<dim3(2, 8, B_), blk, 0, stream>>>(partU, kb_f, partSel);
  topk_rank_k<<<dim3(B_), dim3(512), 0, stream>>>(partSel, idx_ws);
  kbgather_k<<<dim3(B_ * 8), blk, 0, stream>>>(kbf, idx_ws, kb_t);
  // attention (1-D balanced grid; writes ctx = hs_b alias)
  attn_mfma_k<<<dim3(16 * NH_ * B_), blk, 0, stream>>>(fused, kbf, v_t, kb_t, idx_ws, ctx_ws);
  // output projection: split-K gemm256 (64 tiles x 4 slices of K=512) + f32 reduce
  // (round-6 proven path: inter-kernel barrier provides cross-XCD coherence)
  gemm256s<<<dim3(64 * 4), dim3(512), 0, stream>>>(ctx_ws, WTo, partKG, 2048, 2048, 512, 64);
  redp_k<<<dim3((2048 * 2048 / 4 + 255) / 256), blk, 0, stream>>>(
      partKG, out, 4, 2048 * 2048 / 4);
}